// Round 7
// baseline (18245.807 us; speedup 1.0000x reference)
//
#include <hip/hip_runtime.h>
#include <hip/hip_bf16.h>
#include <math.h>

// Problem constants
#define NB 4
#define NS 2048
#define ND 1024
#define NM 4
#define NH 4
#define HDK 128
#define HDV 256
#define CAP 1024
#define NDK 512
#define NDV 1024

// ---------------------------------------------------------------------------
// Router: logits = x @ w_gate (1024x4), softmax, top-2 (ties -> lower index),
// renormalized routing weights. f64 accumulation to match numpy reference's
// discrete top-k decisions as closely as possible.
__global__ __launch_bounds__(256) void router_k(
    const float* __restrict__ X, const float* __restrict__ Wg,
    int* __restrict__ sel, float* __restrict__ rw)
{
  const int lane = threadIdx.x & 63;
  const long long row = (long long)blockIdx.x * 4 + (threadIdx.x >> 6);
  double a0 = 0, a1 = 0, a2 = 0, a3 = 0;
  for (int i = 0; i < 16; ++i) {
    const int d = lane + (i << 6);
    const double xv = (double)X[row * ND + d];
    const float4 wg = *(const float4*)(Wg + ((long long)d << 2));
    a0 += xv * (double)wg.x;
    a1 += xv * (double)wg.y;
    a2 += xv * (double)wg.z;
    a3 += xv * (double)wg.w;
  }
#pragma unroll
  for (int off = 32; off; off >>= 1) {
    a0 += __shfl_xor(a0, off);
    a1 += __shfl_xor(a1, off);
    a2 += __shfl_xor(a2, off);
    a3 += __shfl_xor(a3, off);
  }
  if (lane == 0) {
    const double mx = fmax(fmax(a0, a1), fmax(a2, a3));
    const double p0 = exp(a0 - mx), p1 = exp(a1 - mx);
    const double p2 = exp(a2 - mx), p3 = exp(a3 - mx);
    int i0 = 0; double b0v = p0;
    if (p1 > b0v) { i0 = 1; b0v = p1; }
    if (p2 > b0v) { i0 = 2; b0v = p2; }
    if (p3 > b0v) { i0 = 3; b0v = p3; }
    int i1 = -1; double b1v = -1.0;
    if (i0 != 0 && p0 > b1v) { i1 = 0; b1v = p0; }
    if (i0 != 1 && p1 > b1v) { i1 = 1; b1v = p1; }
    if (i0 != 2 && p2 > b1v) { i1 = 2; b1v = p2; }
    if (i0 != 3 && p3 > b1v) { i1 = 3; b1v = p3; }
    const double s = b0v + b1v;
    sel[row * 2 + 0] = i0;
    sel[row * 2 + 1] = i1;
    rw[row * 2 + 0] = (float)(b0v / s);
    rw[row * 2 + 1] = (float)(b1v / s);
  }
}

// ---------------------------------------------------------------------------
// Dispatch: one wave per (b, mem). Stable rank of each selected slot within
// the (b,mem) group via ballot scan; capacity slot j = r + CAP - count.
// disp_row[(m*NB+b)*CAP + j] = source row in x (b*NS + t) or -1 (padding).
// outpos[b*NS*2 + slot] = j or -1 (dropped).
__global__ __launch_bounds__(64) void dispatch_k(
    const int* __restrict__ sel, int* __restrict__ disp_row,
    int* __restrict__ outpos)
{
  const int b = blockIdx.x >> 2;
  const int m = blockIdx.x & 3;
  const int lane = threadIdx.x;
  const int base_slot = b * (NS * 2);
  // init padding
  for (int j = lane; j < CAP; j += 64)
    disp_row[(m * NB + b) * CAP + j] = -1;
  __syncthreads();
  // pass 1: count
  int count = 0;
  for (int s0 = 0; s0 < NS * 2; s0 += 64) {
    const bool f = (sel[base_slot + s0 + lane] == m);
    count += __popcll(__ballot(f));
  }
  // pass 2: assign slots
  int basec = 0;
  for (int s0 = 0; s0 < NS * 2; s0 += 64) {
    const int slot = s0 + lane;
    const bool f = (sel[base_slot + slot] == m);
    const unsigned long long mask = __ballot(f);
    if (f) {
      const int r = basec + __popcll(mask & ((1ull << lane) - 1ull));
      const int j = r + CAP - count;
      if (j >= 0) {
        disp_row[(m * NB + b) * CAP + j] = b * NS + (slot >> 1);
        outpos[base_slot + slot] = j;
      } else {
        outpos[base_slot + slot] = -1;
      }
    }
    basec += __popcll(mask);
  }
}

// ---------------------------------------------------------------------------
// Generic fp32 tiled GEMM: Y[r][c] = sum_k X[src(r)][k] * W[k][c], 64x64 tile,
// 256 threads, 4x4 per thread. rowmap: gather source rows (-1 -> zero row).
// rows_per_w>0: per-memory weight banks (W += (row0/rows_per_w)*w_stride).
// epi 0: *scale.  epi 2: egk = exp(logsigmoid(acc + bias[c]) / 16).
__global__ __launch_bounds__(256) void gemm_k(
    const float* __restrict__ X, const float* __restrict__ W,
    float* __restrict__ Y, const int* __restrict__ rowmap,
    int N, int K, int rows_per_w, long long w_stride,
    const float* __restrict__ bias, int bias_stride,
    float scale, int epi)
{
  __shared__ float As[16][65];
  __shared__ float Bs[16][64];
  const int tid = threadIdx.x;
  const int row0 = blockIdx.x << 6;
  const int col0 = blockIdx.y << 6;
  const float* Wp = W;
  const float* bp = bias;
  if (rows_per_w > 0) {
    const int mi = row0 / rows_per_w;
    Wp += (long long)mi * w_stride;
    if (bias) bp = bias + mi * bias_stride;
  }
  const int ar = tid >> 2, akq = tid & 3;
  const int bkr = tid >> 4, bnq = tid & 15;
  long long asrc = row0 + ar;
  if (rowmap) asrc = rowmap[row0 + ar];
  const int ty = tid >> 4, tx = tid & 15;
  float acc[4][4] = {{0.f, 0.f, 0.f, 0.f}, {0.f, 0.f, 0.f, 0.f},
                     {0.f, 0.f, 0.f, 0.f}, {0.f, 0.f, 0.f, 0.f}};
  for (int k0 = 0; k0 < K; k0 += 16) {
    float4 av = make_float4(0.f, 0.f, 0.f, 0.f);
    if (asrc >= 0)
      av = *(const float4*)(X + asrc * K + k0 + (akq << 2));
    As[(akq << 2) + 0][ar] = av.x;
    As[(akq << 2) + 1][ar] = av.y;
    As[(akq << 2) + 2][ar] = av.z;
    As[(akq << 2) + 3][ar] = av.w;
    const float4 bv =
        *(const float4*)(Wp + (long long)(k0 + bkr) * N + col0 + (bnq << 2));
    *(float4*)(&Bs[bkr][bnq << 2]) = bv;
    __syncthreads();
#pragma unroll
    for (int kk = 0; kk < 16; ++kk) {
      const float a0 = As[kk][(ty << 2) + 0];
      const float a1 = As[kk][(ty << 2) + 1];
      const float a2 = As[kk][(ty << 2) + 2];
      const float a3 = As[kk][(ty << 2) + 3];
      const float b0 = Bs[kk][(tx << 2) + 0];
      const float b1 = Bs[kk][(tx << 2) + 1];
      const float b2 = Bs[kk][(tx << 2) + 2];
      const float b3 = Bs[kk][(tx << 2) + 3];
      acc[0][0] += a0 * b0; acc[0][1] += a0 * b1; acc[0][2] += a0 * b2; acc[0][3] += a0 * b3;
      acc[1][0] += a1 * b0; acc[1][1] += a1 * b1; acc[1][2] += a1 * b2; acc[1][3] += a1 * b3;
      acc[2][0] += a2 * b0; acc[2][1] += a2 * b1; acc[2][2] += a2 * b2; acc[2][3] += a2 * b3;
      acc[3][0] += a3 * b0; acc[3][1] += a3 * b1; acc[3][2] += a3 * b2; acc[3][3] += a3 * b3;
    }
    __syncthreads();
  }
#pragma unroll
  for (int i = 0; i < 4; ++i) {
    const long long r = row0 + (ty << 2) + i;
#pragma unroll
    for (int j = 0; j < 4; ++j) {
      const int c = col0 + (tx << 2) + j;
      float v = acc[i][j];
      if (epi == 2) {
        v += bp[c];
        const float ls = fminf(v, 0.f) - log1pf(expf(-fabsf(v)));
        v = expf(ls * 0.0625f);  // exp(logsigmoid/GATE_NORM) = decay factor
        Y[r * (long long)N + c] = v;
      } else {
        Y[r * (long long)N + c] = v * scale;
      }
    }
  }
}

// ---------------------------------------------------------------------------
// Low-rank projection t1 = rows @ W1 (K=1024, N=16). One wave per row.
__global__ __launch_bounds__(256) void lowproj_k(
    const float* __restrict__ X, const float* __restrict__ W1,
    float* __restrict__ T1, const int* __restrict__ rowmap,
    int rows_per_w, long long w_stride)
{
  const int lane = threadIdx.x & 63;
  const int row = blockIdx.x * 4 + (threadIdx.x >> 6);
  const float* Wp = W1;
  if (rows_per_w > 0) Wp += (long long)(row / rows_per_w) * w_stride;
  long long src = row;
  if (rowmap) src = rowmap[row];
  float acc[16];
#pragma unroll
  for (int j = 0; j < 16; ++j) acc[j] = 0.f;
  if (src >= 0) {
    for (int i = 0; i < 16; ++i) {
      const int d = lane + (i << 6);
      const float xv = X[src * ND + d];
      const float4* w4 = (const float4*)(Wp + (long long)d * 16);
      const float4 wa = w4[0], wb = w4[1], wc = w4[2], wd = w4[3];
      acc[0] += xv * wa.x; acc[1] += xv * wa.y; acc[2] += xv * wa.z; acc[3] += xv * wa.w;
      acc[4] += xv * wb.x; acc[5] += xv * wb.y; acc[6] += xv * wb.z; acc[7] += xv * wb.w;
      acc[8] += xv * wc.x; acc[9] += xv * wc.y; acc[10] += xv * wc.z; acc[11] += xv * wc.w;
      acc[12] += xv * wd.x; acc[13] += xv * wd.y; acc[14] += xv * wd.z; acc[15] += xv * wd.w;
    }
  }
#pragma unroll
  for (int off = 32; off; off >>= 1) {
#pragma unroll
    for (int j = 0; j < 16; ++j) acc[j] += __shfl_xor(acc[j], off);
  }
  if (lane == 0) {
#pragma unroll
    for (int j = 0; j < 16; ++j) T1[(long long)row * 16 + j] = acc[j];
  }
}

// ---------------------------------------------------------------------------
// Fused-recurrent GLA. One wave per (seq, head, v-chunk of 64). Lane owns one
// v column; state S4[32] (=128 floats) MUST live in VGPRs:
// __launch_bounds__(64, 1) permits up to 512 VGPRs/wave (R5 showed VGPR=76 ->
// the occupancy heuristic spilled the state to scratch -> 11k cycles/step).
__global__ __launch_bounds__(64, 1) void gla_k(
    const float* __restrict__ Q, const float* __restrict__ Kt,
    const float* __restrict__ E, const float* __restrict__ V,
    float* __restrict__ O, int T)
{
  const int lane = threadIdx.x;
  const int vc = blockIdx.x & 3;
  const int h = (blockIdx.x >> 2) & 3;
  const int s = blockIdx.x >> 4;
  const long long qkBase = ((long long)s * T) * 512 + h * 128;
  const long long vBase = ((long long)s * T) * 1024 + h * 256 + vc * 64 + lane;
  float4 S4[32];
#pragma unroll
  for (int i = 0; i < 32; ++i) S4[i] = make_float4(0.f, 0.f, 0.f, 0.f);
  for (int t = 0; t < T; ++t) {
    const float4* qp = (const float4*)(Q + qkBase + (long long)t * 512);
    const float4* kp = (const float4*)(Kt + qkBase + (long long)t * 512);
    const float4* ep = (const float4*)(E + qkBase + (long long)t * 512);
    const float vv = V[vBase + (long long)t * 1024];
    float oacc = 0.f;
#pragma unroll
    for (int kk = 0; kk < 32; ++kk) {
      const float4 k4 = kp[kk];
      const float4 e4 = ep[kk];
      const float4 q4 = qp[kk];
      float4 sv = S4[kk];
      sv.x = sv.x * e4.x + k4.x * vv; oacc += q4.x * sv.x;
      sv.y = sv.y * e4.y + k4.y * vv; oacc += q4.y * sv.y;
      sv.z = sv.z * e4.z + k4.z * vv; oacc += q4.z * sv.z;
      sv.w = sv.w * e4.w + k4.w * vv; oacc += q4.w * sv.w;
      S4[kk] = sv;
    }
    O[vBase + (long long)t * 1024] = oacc;
  }
}

// ---------------------------------------------------------------------------
// Reconstruct: o_comb[b,t,:] += sum_j rw[b,t,j] * o_mem[sel[j], b, pos[j], :]
__global__ __launch_bounds__(256) void recon_k(
    float* __restrict__ Ocomb, const float* __restrict__ Omem,
    const int* __restrict__ sel, const float* __restrict__ rw,
    const int* __restrict__ outpos)
{
  const long long row = blockIdx.x;
  const int b = (int)(row >> 11);
  const int tq = threadIdx.x;
  float4 acc = *(float4*)(Ocomb + row * 1024 + tq * 4);
#pragma unroll
  for (int j = 0; j < 2; ++j) {
    const int slot = ((int)row) * 2 + j;
    const int pos = outpos[slot];
    if (pos >= 0) {
      const int mem = sel[slot];
      const float w = rw[slot];
      const long long orow = (long long)(mem * NB + b) * CAP + pos;
      const float4 om = *(const float4*)(Omem + orow * 1024 + tq * 4);
      acc.x += w * om.x; acc.y += w * om.y; acc.z += w * om.z; acc.w += w * om.w;
    }
  }
  *(float4*)(Ocomb + row * 1024 + tq * 4) = acc;
}

// ---------------------------------------------------------------------------
// Gated RMSNorm: per (row, head): o*rsqrt(mean(o^2)+eps)*norm_w * swish(g)
__global__ __launch_bounds__(256) void normgate_k(
    float* __restrict__ O, const float* __restrict__ G,
    const float* __restrict__ NW)
{
  const long long row = blockIdx.x;
  const int h = threadIdx.x >> 6, lane = threadIdx.x & 63;
  const long long base = row * 1024 + h * 256 + lane * 4;
  float4 o4 = *(float4*)(O + base);
  float ss = o4.x * o4.x + o4.y * o4.y + o4.z * o4.z + o4.w * o4.w;
#pragma unroll
  for (int off = 32; off; off >>= 1) ss += __shfl_xor(ss, off);
  const float inv = rsqrtf(ss * (1.f / 256.f) + 1e-5f);
  const float4 g4 = *(const float4*)(G + base);
  const float4 nw = *(const float4*)(NW + lane * 4);
  float4 y;
  y.x = o4.x * inv * nw.x * (g4.x / (1.f + expf(-g4.x)));
  y.y = o4.y * inv * nw.y * (g4.y / (1.f + expf(-g4.y)));
  y.z = o4.z * inv * nw.z * (g4.z / (1.f + expf(-g4.z)));
  y.w = o4.w * inv * nw.w * (g4.w / (1.f + expf(-g4.w)));
  *(float4*)(O + base) = y;
}

// ---------------------------------------------------------------------------
// Workspace layout (225.2 MB total; 303 MB overflowed the arena).
//   A (8.39M fl): routed Q -> shared Q (first half) -> gbuf (all)
//   B (8.39M fl): routed K -> shared Ks (first half)
//   C (8.39M fl): routed GK -> shared GKs (first half)
//   D (16.78M fl): routed V -> shared V (first half) + ocomb (second half)
//   E (16.78M fl): omem
// Routed path runs FIRST, shared path reuses the same buffers.
extern "C" void kernel_launch(void* const* d_in, const int* in_sizes, int n_in,
                              void* d_out, int out_size, void* d_ws, size_t ws_size,
                              hipStream_t stream) {
  (void)in_sizes; (void)n_in; (void)out_size; (void)ws_size;
  const float* x      = (const float*)d_in[0];
  const float* w_gate = (const float*)d_in[1];
  const float* w_q    = (const float*)d_in[2];
  const float* w_k    = (const float*)d_in[3];
  const float* w_v    = (const float*)d_in[4];
  const float* w_gk1  = (const float*)d_in[5];
  const float* w_gk2  = (const float*)d_in[6];
  const float* b_gk   = (const float*)d_in[7];
  const float* w_ks   = (const float*)d_in[8];
  const float* w_vs   = (const float*)d_in[9];
  const float* w_gk1s = (const float*)d_in[10];
  const float* w_gk2s = (const float*)d_in[11];
  const float* b_gks  = (const float*)d_in[12];
  const float* w_g    = (const float*)d_in[13];
  const float* w_o    = (const float*)d_in[14];
  const float* norm_w = (const float*)d_in[15];
  float* out = (float*)d_out;  // float32 output

  float* ws = (float*)d_ws;
  size_t off = 0;
  int* selb    = (int*)(ws + off); off += 16384;      // (B,S,2)
  float* rwb   = ws + off;         off += 16384;      // (B,S,2)
  int* outpos  = (int*)(ws + off); off += 16384;      // (B,S,2)
  int* dispr   = (int*)(ws + off); off += 16384;      // (M,B,CAP)
  float* t1    = ws + off;         off += 262144;     // up to 16384 x 16
  float* A     = ws + off;         off += 8388608;    // 16384 x 512
  float* B_    = ws + off;         off += 8388608;    // 16384 x 512
  float* C_    = ws + off;         off += 8388608;    // 16384 x 512
  float* D_    = ws + off;         off += 16777216;   // 16384 x 1024
  float* E_    = ws + off;         off += 16777216;   // (M,B,CAP,1024)
  float* ocomb = D_ + 8388608;                        // (B,S,1024) in D upper half
  float* gbuf  = A;                                   // (B,S,1024) in A after GLA

  const float qscale = 0.08838834764831845f;  // 128^-0.5

  router_k<<<2048, 256, 0, stream>>>(x, w_gate, selb, rwb);
  dispatch_k<<<16, 64, 0, stream>>>(selb, dispr, outpos);

  dim3 g128_8(128, 8), g128_16(128, 16), g256_8(256, 8), g256_16(256, 16);

  // ---- routed path (16384 gathered rows) ----
  gemm_k<<<g256_8, 256, 0, stream>>>(x, w_q, A, dispr, 512, 1024, 0, 0, nullptr, 0, qscale, 0);
  gemm_k<<<g256_8, 256, 0, stream>>>(x, w_k, B_, dispr, 512, 1024, NB * CAP, (long long)ND * NDK, nullptr, 0, 1.f, 0);
  gemm_k<<<g256_16, 256, 0, stream>>>(x, w_v, D_, dispr, 1024, 1024, NB * CAP, (long long)ND * NDV, nullptr, 0, 1.f, 0);
  lowproj_k<<<4096, 256, 0, stream>>>(x, w_gk1, t1, dispr, NB * CAP, (long long)ND * 16);
  gemm_k<<<g256_8, 256, 0, stream>>>(t1, w_gk2, C_, nullptr, 512, 16, NB * CAP, 16LL * NDK, b_gk, NDK, 1.f, 2);
  gla_k<<<256, 64, 0, stream>>>(A, B_, C_, D_, E_, CAP);   // -> omem

  // ---- shared path (8192 rows), reusing lower halves of A/B_/C_/D_ ----
  gemm_k<<<g128_8, 256, 0, stream>>>(x, w_q, A, nullptr, 512, 1024, 0, 0, nullptr, 0, qscale, 0);
  gemm_k<<<g128_8, 256, 0, stream>>>(x, w_ks, B_, nullptr, 512, 1024, 0, 0, nullptr, 0, 1.f, 0);
  gemm_k<<<g128_16, 256, 0, stream>>>(x, w_vs, D_, nullptr, 1024, 1024, 0, 0, nullptr, 0, 1.f, 0);
  lowproj_k<<<2048, 256, 0, stream>>>(x, w_gk1s, t1, nullptr, 0, 0);
  gemm_k<<<g128_8, 256, 0, stream>>>(t1, w_gk2s, C_, nullptr, 512, 16, 0, 0, b_gks, 0, 1.f, 2);
  gla_k<<<64, 64, 0, stream>>>(A, B_, C_, D_, ocomb, NS);  // reads D lower, writes D upper

  // ---- combine + epilogue ----
  gemm_k<<<g128_16, 256, 0, stream>>>(x, w_g, gbuf, nullptr, 1024, 1024, 0, 0, nullptr, 0, 1.f, 0);
  recon_k<<<8192, 256, 0, stream>>>(ocomb, E_, selb, rwb, outpos);
  normgate_k<<<8192, 256, 0, stream>>>(ocomb, gbuf, norm_w);
  gemm_k<<<g128_16, 256, 0, stream>>>(ocomb, w_o, out, nullptr, 1024, 1024, 0, 0, nullptr, 0, 1.f, 0);
}

// Round 8
// 14846.178 us; speedup vs baseline: 1.2290x; 1.2290x over previous
//
#include <hip/hip_runtime.h>
#include <hip/hip_bf16.h>
#include <math.h>

// Problem constants
#define NB 4
#define NS 2048
#define ND 1024
#define NM 4
#define NH 4
#define HDK 128
#define HDV 256
#define CAP 1024
#define NDK 512
#define NDV 1024

// ---------------------------------------------------------------------------
// Router: logits = x @ w_gate (1024x4), softmax, top-2 (ties -> lower index),
// renormalized routing weights. f64 accumulation to match numpy reference's
// discrete top-k decisions as closely as possible.
__global__ __launch_bounds__(256) void router_k(
    const float* __restrict__ X, const float* __restrict__ Wg,
    int* __restrict__ sel, float* __restrict__ rw)
{
  const int lane = threadIdx.x & 63;
  const long long row = (long long)blockIdx.x * 4 + (threadIdx.x >> 6);
  double a0 = 0, a1 = 0, a2 = 0, a3 = 0;
  for (int i = 0; i < 16; ++i) {
    const int d = lane + (i << 6);
    const double xv = (double)X[row * ND + d];
    const float4 wg = *(const float4*)(Wg + ((long long)d << 2));
    a0 += xv * (double)wg.x;
    a1 += xv * (double)wg.y;
    a2 += xv * (double)wg.z;
    a3 += xv * (double)wg.w;
  }
#pragma unroll
  for (int off = 32; off; off >>= 1) {
    a0 += __shfl_xor(a0, off);
    a1 += __shfl_xor(a1, off);
    a2 += __shfl_xor(a2, off);
    a3 += __shfl_xor(a3, off);
  }
  if (lane == 0) {
    const double mx = fmax(fmax(a0, a1), fmax(a2, a3));
    const double p0 = exp(a0 - mx), p1 = exp(a1 - mx);
    const double p2 = exp(a2 - mx), p3 = exp(a3 - mx);
    int i0 = 0; double b0v = p0;
    if (p1 > b0v) { i0 = 1; b0v = p1; }
    if (p2 > b0v) { i0 = 2; b0v = p2; }
    if (p3 > b0v) { i0 = 3; b0v = p3; }
    int i1 = -1; double b1v = -1.0;
    if (i0 != 0 && p0 > b1v) { i1 = 0; b1v = p0; }
    if (i0 != 1 && p1 > b1v) { i1 = 1; b1v = p1; }
    if (i0 != 2 && p2 > b1v) { i1 = 2; b1v = p2; }
    if (i0 != 3 && p3 > b1v) { i1 = 3; b1v = p3; }
    const double s = b0v + b1v;
    sel[row * 2 + 0] = i0;
    sel[row * 2 + 1] = i1;
    rw[row * 2 + 0] = (float)(b0v / s);
    rw[row * 2 + 1] = (float)(b1v / s);
  }
}

// ---------------------------------------------------------------------------
// Dispatch: one wave per (b, mem). Stable rank of each selected slot within
// the (b,mem) group via ballot scan; capacity slot j = r + CAP - count.
// disp_row[(m*NB+b)*CAP + j] = source row in x (b*NS + t) or -1 (padding).
// outpos[b*NS*2 + slot] = j or -1 (dropped).
__global__ __launch_bounds__(64) void dispatch_k(
    const int* __restrict__ sel, int* __restrict__ disp_row,
    int* __restrict__ outpos)
{
  const int b = blockIdx.x >> 2;
  const int m = blockIdx.x & 3;
  const int lane = threadIdx.x;
  const int base_slot = b * (NS * 2);
  // init padding
  for (int j = lane; j < CAP; j += 64)
    disp_row[(m * NB + b) * CAP + j] = -1;
  __syncthreads();
  // pass 1: count
  int count = 0;
  for (int s0 = 0; s0 < NS * 2; s0 += 64) {
    const bool f = (sel[base_slot + s0 + lane] == m);
    count += __popcll(__ballot(f));
  }
  // pass 2: assign slots
  int basec = 0;
  for (int s0 = 0; s0 < NS * 2; s0 += 64) {
    const int slot = s0 + lane;
    const bool f = (sel[base_slot + slot] == m);
    const unsigned long long mask = __ballot(f);
    if (f) {
      const int r = basec + __popcll(mask & ((1ull << lane) - 1ull));
      const int j = r + CAP - count;
      if (j >= 0) {
        disp_row[(m * NB + b) * CAP + j] = b * NS + (slot >> 1);
        outpos[base_slot + slot] = j;
      } else {
        outpos[base_slot + slot] = -1;
      }
    }
    basec += __popcll(mask);
  }
}

// ---------------------------------------------------------------------------
// Generic fp32 tiled GEMM: Y[r][c] = sum_k X[src(r)][k] * W[k][c], 64x64 tile,
// 256 threads, 4x4 per thread. rowmap: gather source rows (-1 -> zero row).
// rows_per_w>0: per-memory weight banks (W += (row0/rows_per_w)*w_stride).
// epi 0: *scale.  epi 2: egk = exp(logsigmoid(acc + bias[c]) / 16).
__global__ __launch_bounds__(256) void gemm_k(
    const float* __restrict__ X, const float* __restrict__ W,
    float* __restrict__ Y, const int* __restrict__ rowmap,
    int N, int K, int rows_per_w, long long w_stride,
    const float* __restrict__ bias, int bias_stride,
    float scale, int epi)
{
  __shared__ float As[16][65];
  __shared__ float Bs[16][64];
  const int tid = threadIdx.x;
  const int row0 = blockIdx.x << 6;
  const int col0 = blockIdx.y << 6;
  const float* Wp = W;
  const float* bp = bias;
  if (rows_per_w > 0) {
    const int mi = row0 / rows_per_w;
    Wp += (long long)mi * w_stride;
    if (bias) bp = bias + mi * bias_stride;
  }
  const int ar = tid >> 2, akq = tid & 3;
  const int bkr = tid >> 4, bnq = tid & 15;
  long long asrc = row0 + ar;
  if (rowmap) asrc = rowmap[row0 + ar];
  const int ty = tid >> 4, tx = tid & 15;
  float acc[4][4] = {{0.f, 0.f, 0.f, 0.f}, {0.f, 0.f, 0.f, 0.f},
                     {0.f, 0.f, 0.f, 0.f}, {0.f, 0.f, 0.f, 0.f}};
  for (int k0 = 0; k0 < K; k0 += 16) {
    float4 av = make_float4(0.f, 0.f, 0.f, 0.f);
    if (asrc >= 0)
      av = *(const float4*)(X + asrc * K + k0 + (akq << 2));
    As[(akq << 2) + 0][ar] = av.x;
    As[(akq << 2) + 1][ar] = av.y;
    As[(akq << 2) + 2][ar] = av.z;
    As[(akq << 2) + 3][ar] = av.w;
    const float4 bv =
        *(const float4*)(Wp + (long long)(k0 + bkr) * N + col0 + (bnq << 2));
    *(float4*)(&Bs[bkr][bnq << 2]) = bv;
    __syncthreads();
#pragma unroll
    for (int kk = 0; kk < 16; ++kk) {
      const float a0 = As[kk][(ty << 2) + 0];
      const float a1 = As[kk][(ty << 2) + 1];
      const float a2 = As[kk][(ty << 2) + 2];
      const float a3 = As[kk][(ty << 2) + 3];
      const float b0 = Bs[kk][(tx << 2) + 0];
      const float b1 = Bs[kk][(tx << 2) + 1];
      const float b2 = Bs[kk][(tx << 2) + 2];
      const float b3 = Bs[kk][(tx << 2) + 3];
      acc[0][0] += a0 * b0; acc[0][1] += a0 * b1; acc[0][2] += a0 * b2; acc[0][3] += a0 * b3;
      acc[1][0] += a1 * b0; acc[1][1] += a1 * b1; acc[1][2] += a1 * b2; acc[1][3] += a1 * b3;
      acc[2][0] += a2 * b0; acc[2][1] += a2 * b1; acc[2][2] += a2 * b2; acc[2][3] += a2 * b3;
      acc[3][0] += a3 * b0; acc[3][1] += a3 * b1; acc[3][2] += a3 * b2; acc[3][3] += a3 * b3;
    }
    __syncthreads();
  }
#pragma unroll
  for (int i = 0; i < 4; ++i) {
    const long long r = row0 + (ty << 2) + i;
#pragma unroll
    for (int j = 0; j < 4; ++j) {
      const int c = col0 + (tx << 2) + j;
      float v = acc[i][j];
      if (epi == 2) {
        v += bp[c];
        const float ls = fminf(v, 0.f) - log1pf(expf(-fabsf(v)));
        v = expf(ls * 0.0625f);  // exp(logsigmoid/GATE_NORM) = decay factor
        Y[r * (long long)N + c] = v;
      } else {
        Y[r * (long long)N + c] = v * scale;
      }
    }
  }
}

// ---------------------------------------------------------------------------
// Low-rank projection t1 = rows @ W1 (K=1024, N=16). One wave per row.
__global__ __launch_bounds__(256) void lowproj_k(
    const float* __restrict__ X, const float* __restrict__ W1,
    float* __restrict__ T1, const int* __restrict__ rowmap,
    int rows_per_w, long long w_stride)
{
  const int lane = threadIdx.x & 63;
  const int row = blockIdx.x * 4 + (threadIdx.x >> 6);
  const float* Wp = W1;
  if (rows_per_w > 0) Wp += (long long)(row / rows_per_w) * w_stride;
  long long src = row;
  if (rowmap) src = rowmap[row];
  float acc[16];
#pragma unroll
  for (int j = 0; j < 16; ++j) acc[j] = 0.f;
  if (src >= 0) {
    for (int i = 0; i < 16; ++i) {
      const int d = lane + (i << 6);
      const float xv = X[src * ND + d];
      const float4* w4 = (const float4*)(Wp + (long long)d * 16);
      const float4 wa = w4[0], wb = w4[1], wc = w4[2], wd = w4[3];
      acc[0] += xv * wa.x; acc[1] += xv * wa.y; acc[2] += xv * wa.z; acc[3] += xv * wa.w;
      acc[4] += xv * wb.x; acc[5] += xv * wb.y; acc[6] += xv * wb.z; acc[7] += xv * wb.w;
      acc[8] += xv * wc.x; acc[9] += xv * wc.y; acc[10] += xv * wc.z; acc[11] += xv * wc.w;
      acc[12] += xv * wd.x; acc[13] += xv * wd.y; acc[14] += xv * wd.z; acc[15] += xv * wd.w;
    }
  }
#pragma unroll
  for (int off = 32; off; off >>= 1) {
#pragma unroll
    for (int j = 0; j < 16; ++j) acc[j] += __shfl_xor(acc[j], off);
  }
  if (lane == 0) {
#pragma unroll
    for (int j = 0; j < 16; ++j) T1[(long long)row * 16 + j] = acc[j];
  }
}

// ---------------------------------------------------------------------------
// Fused-recurrent GLA. One wave per (seq, head, v-chunk of 64). Lane owns one
// v column. State = 32 NAMED float4 variables (no array -> no alloca -> the
// compiler CANNOT put it in scratch). R5/R7 showed float S[128] and float4
// S4[32] both stayed allocas (VGPR_Count=76, 9.7ms: full scratch round-trip
// each step) regardless of __launch_bounds__ - AMDGPU PromoteAlloca declines
// the 512B array. Named SSA values are the guaranteed fix (rule #20).
#define GLA_DECL(i) float4 s##i = make_float4(0.f, 0.f, 0.f, 0.f);
#define GLA_STEP(i)                                                          \
  {                                                                          \
    const float4 k4 = kp[i];                                                 \
    const float4 e4 = ep[i];                                                 \
    const float4 q4 = qp[i];                                                 \
    s##i.x = fmaf(e4.x, s##i.x, k4.x * vv); oacc = fmaf(q4.x, s##i.x, oacc); \
    s##i.y = fmaf(e4.y, s##i.y, k4.y * vv); oacc = fmaf(q4.y, s##i.y, oacc); \
    s##i.z = fmaf(e4.z, s##i.z, k4.z * vv); oacc = fmaf(q4.z, s##i.z, oacc); \
    s##i.w = fmaf(e4.w, s##i.w, k4.w * vv); oacc = fmaf(q4.w, s##i.w, oacc); \
  }
__global__ __launch_bounds__(64, 1) void gla_k(
    const float* __restrict__ Q, const float* __restrict__ Kt,
    const float* __restrict__ E, const float* __restrict__ V,
    float* __restrict__ O, int T)
{
  const int lane = threadIdx.x;
  const int vc = blockIdx.x & 3;
  const int h = (blockIdx.x >> 2) & 3;
  const int s = blockIdx.x >> 4;
  const long long qkBase = ((long long)s * T) * 512 + h * 128;
  const long long vBase = ((long long)s * T) * 1024 + h * 256 + vc * 64 + lane;
  GLA_DECL(0)  GLA_DECL(1)  GLA_DECL(2)  GLA_DECL(3)
  GLA_DECL(4)  GLA_DECL(5)  GLA_DECL(6)  GLA_DECL(7)
  GLA_DECL(8)  GLA_DECL(9)  GLA_DECL(10) GLA_DECL(11)
  GLA_DECL(12) GLA_DECL(13) GLA_DECL(14) GLA_DECL(15)
  GLA_DECL(16) GLA_DECL(17) GLA_DECL(18) GLA_DECL(19)
  GLA_DECL(20) GLA_DECL(21) GLA_DECL(22) GLA_DECL(23)
  GLA_DECL(24) GLA_DECL(25) GLA_DECL(26) GLA_DECL(27)
  GLA_DECL(28) GLA_DECL(29) GLA_DECL(30) GLA_DECL(31)
  for (int t = 0; t < T; ++t) {
    const float4* qp = (const float4*)(Q + qkBase + (long long)t * 512);
    const float4* kp = (const float4*)(Kt + qkBase + (long long)t * 512);
    const float4* ep = (const float4*)(E + qkBase + (long long)t * 512);
    const float vv = V[vBase + (long long)t * 1024];
    float oacc = 0.f;
    GLA_STEP(0)  GLA_STEP(1)  GLA_STEP(2)  GLA_STEP(3)
    GLA_STEP(4)  GLA_STEP(5)  GLA_STEP(6)  GLA_STEP(7)
    GLA_STEP(8)  GLA_STEP(9)  GLA_STEP(10) GLA_STEP(11)
    GLA_STEP(12) GLA_STEP(13) GLA_STEP(14) GLA_STEP(15)
    GLA_STEP(16) GLA_STEP(17) GLA_STEP(18) GLA_STEP(19)
    GLA_STEP(20) GLA_STEP(21) GLA_STEP(22) GLA_STEP(23)
    GLA_STEP(24) GLA_STEP(25) GLA_STEP(26) GLA_STEP(27)
    GLA_STEP(28) GLA_STEP(29) GLA_STEP(30) GLA_STEP(31)
    O[vBase + (long long)t * 1024] = oacc;
  }
}

// ---------------------------------------------------------------------------
// Reconstruct: o_comb[b,t,:] += sum_j rw[b,t,j] * o_mem[sel[j], b, pos[j], :]
__global__ __launch_bounds__(256) void recon_k(
    float* __restrict__ Ocomb, const float* __restrict__ Omem,
    const int* __restrict__ sel, const float* __restrict__ rw,
    const int* __restrict__ outpos)
{
  const long long row = blockIdx.x;
  const int b = (int)(row >> 11);
  const int tq = threadIdx.x;
  float4 acc = *(float4*)(Ocomb + row * 1024 + tq * 4);
#pragma unroll
  for (int j = 0; j < 2; ++j) {
    const int slot = ((int)row) * 2 + j;
    const int pos = outpos[slot];
    if (pos >= 0) {
      const int mem = sel[slot];
      const float w = rw[slot];
      const long long orow = (long long)(mem * NB + b) * CAP + pos;
      const float4 om = *(const float4*)(Omem + orow * 1024 + tq * 4);
      acc.x += w * om.x; acc.y += w * om.y; acc.z += w * om.z; acc.w += w * om.w;
    }
  }
  *(float4*)(Ocomb + row * 1024 + tq * 4) = acc;
}

// ---------------------------------------------------------------------------
// Gated RMSNorm: per (row, head): o*rsqrt(mean(o^2)+eps)*norm_w * swish(g)
__global__ __launch_bounds__(256) void normgate_k(
    float* __restrict__ O, const float* __restrict__ G,
    const float* __restrict__ NW)
{
  const long long row = blockIdx.x;
  const int h = threadIdx.x >> 6, lane = threadIdx.x & 63;
  const long long base = row * 1024 + h * 256 + lane * 4;
  float4 o4 = *(float4*)(O + base);
  float ss = o4.x * o4.x + o4.y * o4.y + o4.z * o4.z + o4.w * o4.w;
#pragma unroll
  for (int off = 32; off; off >>= 1) ss += __shfl_xor(ss, off);
  const float inv = rsqrtf(ss * (1.f / 256.f) + 1e-5f);
  const float4 g4 = *(const float4*)(G + base);
  const float4 nw = *(const float4*)(NW + lane * 4);
  float4 y;
  y.x = o4.x * inv * nw.x * (g4.x / (1.f + expf(-g4.x)));
  y.y = o4.y * inv * nw.y * (g4.y / (1.f + expf(-g4.y)));
  y.z = o4.z * inv * nw.z * (g4.z / (1.f + expf(-g4.z)));
  y.w = o4.w * inv * nw.w * (g4.w / (1.f + expf(-g4.w)));
  *(float4*)(O + base) = y;
}

// ---------------------------------------------------------------------------
// Workspace layout (225.2 MB total; 303 MB overflowed the arena).
//   A (8.39M fl): routed Q -> shared Q (first half) -> gbuf (all)
//   B (8.39M fl): routed K -> shared Ks (first half)
//   C (8.39M fl): routed GK -> shared GKs (first half)
//   D (16.78M fl): routed V -> shared V (first half) + ocomb (second half)
//   E (16.78M fl): omem
// Routed path runs FIRST, shared path reuses the same buffers.
extern "C" void kernel_launch(void* const* d_in, const int* in_sizes, int n_in,
                              void* d_out, int out_size, void* d_ws, size_t ws_size,
                              hipStream_t stream) {
  (void)in_sizes; (void)n_in; (void)out_size; (void)ws_size;
  const float* x      = (const float*)d_in[0];
  const float* w_gate = (const float*)d_in[1];
  const float* w_q    = (const float*)d_in[2];
  const float* w_k    = (const float*)d_in[3];
  const float* w_v    = (const float*)d_in[4];
  const float* w_gk1  = (const float*)d_in[5];
  const float* w_gk2  = (const float*)d_in[6];
  const float* b_gk   = (const float*)d_in[7];
  const float* w_ks   = (const float*)d_in[8];
  const float* w_vs   = (const float*)d_in[9];
  const float* w_gk1s = (const float*)d_in[10];
  const float* w_gk2s = (const float*)d_in[11];
  const float* b_gks  = (const float*)d_in[12];
  const float* w_g    = (const float*)d_in[13];
  const float* w_o    = (const float*)d_in[14];
  const float* norm_w = (const float*)d_in[15];
  float* out = (float*)d_out;  // float32 output

  float* ws = (float*)d_ws;
  size_t off = 0;
  int* selb    = (int*)(ws + off); off += 16384;      // (B,S,2)
  float* rwb   = ws + off;         off += 16384;      // (B,S,2)
  int* outpos  = (int*)(ws + off); off += 16384;      // (B,S,2)
  int* dispr   = (int*)(ws + off); off += 16384;      // (M,B,CAP)
  float* t1    = ws + off;         off += 262144;     // up to 16384 x 16
  float* A     = ws + off;         off += 8388608;    // 16384 x 512
  float* B_    = ws + off;         off += 8388608;    // 16384 x 512
  float* C_    = ws + off;         off += 8388608;    // 16384 x 512
  float* D_    = ws + off;         off += 16777216;   // 16384 x 1024
  float* E_    = ws + off;         off += 16777216;   // (M,B,CAP,1024)
  float* ocomb = D_ + 8388608;                        // (B,S,1024) in D upper half
  float* gbuf  = A;                                   // (B,S,1024) in A after GLA

  const float qscale = 0.08838834764831845f;  // 128^-0.5

  router_k<<<2048, 256, 0, stream>>>(x, w_gate, selb, rwb);
  dispatch_k<<<16, 64, 0, stream>>>(selb, dispr, outpos);

  dim3 g128_8(128, 8), g128_16(128, 16), g256_8(256, 8), g256_16(256, 16);

  // ---- routed path (16384 gathered rows) ----
  gemm_k<<<g256_8, 256, 0, stream>>>(x, w_q, A, dispr, 512, 1024, 0, 0, nullptr, 0, qscale, 0);
  gemm_k<<<g256_8, 256, 0, stream>>>(x, w_k, B_, dispr, 512, 1024, NB * CAP, (long long)ND * NDK, nullptr, 0, 1.f, 0);
  gemm_k<<<g256_16, 256, 0, stream>>>(x, w_v, D_, dispr, 1024, 1024, NB * CAP, (long long)ND * NDV, nullptr, 0, 1.f, 0);
  lowproj_k<<<4096, 256, 0, stream>>>(x, w_gk1, t1, dispr, NB * CAP, (long long)ND * 16);
  gemm_k<<<g256_8, 256, 0, stream>>>(t1, w_gk2, C_, nullptr, 512, 16, NB * CAP, 16LL * NDK, b_gk, NDK, 1.f, 2);
  gla_k<<<256, 64, 0, stream>>>(A, B_, C_, D_, E_, CAP);   // -> omem

  // ---- shared path (8192 rows), reusing lower halves of A/B_/C_/D_ ----
  gemm_k<<<g128_8, 256, 0, stream>>>(x, w_q, A, nullptr, 512, 1024, 0, 0, nullptr, 0, qscale, 0);
  gemm_k<<<g128_8, 256, 0, stream>>>(x, w_ks, B_, nullptr, 512, 1024, 0, 0, nullptr, 0, 1.f, 0);
  gemm_k<<<g128_16, 256, 0, stream>>>(x, w_vs, D_, nullptr, 1024, 1024, 0, 0, nullptr, 0, 1.f, 0);
  lowproj_k<<<2048, 256, 0, stream>>>(x, w_gk1s, t1, nullptr, 0, 0);
  gemm_k<<<g128_8, 256, 0, stream>>>(t1, w_gk2s, C_, nullptr, 512, 16, 0, 0, b_gks, 0, 1.f, 2);
  gla_k<<<64, 64, 0, stream>>>(A, B_, C_, D_, ocomb, NS);  // reads D lower, writes D upper

  // ---- combine + epilogue ----
  gemm_k<<<g128_16, 256, 0, stream>>>(x, w_g, gbuf, nullptr, 1024, 1024, 0, 0, nullptr, 0, 1.f, 0);
  recon_k<<<8192, 256, 0, stream>>>(ocomb, E_, selb, rwb, outpos);
  normgate_k<<<8192, 256, 0, stream>>>(ocomb, gbuf, norm_w);
  gemm_k<<<g128_16, 256, 0, stream>>>(ocomb, w_o, out, nullptr, 1024, 1024, 0, 0, nullptr, 0, 1.f, 0);
}